// Round 4
// baseline (141.567 us; speedup 1.0000x reference)
//
#include <hip/hip_runtime.h>
#include <cstdint>
#include <cstddef>

#define LOG2E 1.44269504088896340736f

typedef float  f32x16 __attribute__((ext_vector_type(16)));
typedef __bf16 bf16x8 __attribute__((ext_vector_type(8)));

union BF8 { bf16x8 v; uint u[4]; ushort us[8]; };

// pack two floats to bf16 pair (round-half-up), a -> lo16, b -> hi16
__device__ __forceinline__ uint pack_bf(float a, float b) {
    uint ua = __float_as_uint(a) + 0x8000u;
    uint ub = __float_as_uint(b) + 0x8000u;
    return __builtin_amdgcn_perm(ub, ua, 0x07060302u);
}
// truncating pack (1 op). Used for P only: l sums the same truncated P via the
// ones-row, so the /l normalization cancels the truncation bias to first order.
__device__ __forceinline__ uint pack_bf_trunc(float a, float b) {
    return __builtin_amdgcn_perm(__float_as_uint(b), __float_as_uint(a), 0x07060302u);
}
__device__ __forceinline__ float bf_lo(uint u) { return __uint_as_float(u << 16); }
__device__ __forceinline__ float bf_hi(uint u) { return __uint_as_float(u & 0xFFFF0000u); }

// ---------------------------------------------------------------------------
// ln_cast (+ fused weight convert): blocks 0..255 do per-pixel LayerNorm over
// 256 channels, emitting xn_bf / xr_bf row-major [b*4096+n][256] bf16.
// Blocks 256..351 convert qkv_w/c1w/out_w to bf16 (Q rows pre-scaled).
// grid 352 x 256.
// ---------------------------------------------------------------------------
__global__ __launch_bounds__(256) void ln_cast_kernel(
    const float* __restrict__ x, const float* __restrict__ nw, const float* __restrict__ nb,
    const float* __restrict__ qkv_w, const float* __restrict__ c1w, const float* __restrict__ out_w,
    ushort* __restrict__ xnb, ushort* __restrict__ xrb,
    ushort* __restrict__ qkvw_b, ushort* __restrict__ c1w_b, ushort* __restrict__ ow_b)
{
    __shared__ uint  xp[32 * 144];   // [px][c/2] bf16 pairs, stride 144 (2-way free)
    __shared__ float red1[256], red2[256];
    __shared__ float muS[32], rsS[32];

    const int t  = threadIdx.x;
    const int bi = blockIdx.x;

    if (bi >= 256) {                 // weight-convert path
        const int g = ((bi - 256) * 256 + t) * 4;
        const float* src; ushort* dst; int off; float sc = 1.f;
        if (g < 49152)      { src = qkv_w; dst = qkvw_b; off = g;
                              if (g < 16384) sc = 0.25f * LOG2E; }
        else if (g < 81920) { src = c1w;   dst = c1w_b;  off = g - 49152; }
        else                { src = out_w; dst = ow_b;   off = g - 81920; }
        float4 v = *(const float4*)(src + off);
        uint2 pk;
        pk.x = pack_bf(v.x * sc, v.y * sc);
        pk.y = pack_bf(v.z * sc, v.w * sc);
        *(uint2*)(dst + off) = pk;
        return;
    }

    const int b  = bi >> 7;
    const int n0 = (bi & 127) * 32;
    const int j  = t & 31;          // px
    const int cg = t >> 5;          // channel group (32 c each)
    const size_t xb = (size_t)b * 256 * 4096 + n0 + j;

    float v[32];
    #pragma unroll
    for (int i = 0; i < 32; ++i) v[i] = x[xb + (size_t)(cg * 32 + i) * 4096];
    float s1 = 0.f, s2 = 0.f;
    #pragma unroll
    for (int i = 0; i < 32; ++i) { s1 += v[i]; s2 += v[i] * v[i]; }
    #pragma unroll
    for (int i = 0; i < 16; ++i)
        xp[j * 144 + cg * 16 + i] = pack_bf(v[2 * i], v[2 * i + 1]);
    red1[t] = s1; red2[t] = s2;
    __syncthreads();
    if (t < 32) {
        float a = 0.f, q = 0.f;
        #pragma unroll
        for (int g2 = 0; g2 < 8; ++g2) { a += red1[g2 * 32 + t]; q += red2[g2 * 32 + t]; }
        float mu  = a * (1.f / 256.f);
        float var = q * (1.f / 256.f) - mu * mu;
        muS[t] = mu; rsS[t] = rsqrtf(fmaxf(var, 0.f) + 1e-5f);
    }
    __syncthreads();

    for (int it = 0; it < 4; ++it) {
        int lin = it * 256 + t;
        int px = lin >> 5, q = lin & 31;          // q = uint4 slot (8 bf16)
        uint4 raw = *(uint4*)&xp[px * 144 + q * 4];
        size_t row = (size_t)bi * 32 + px;        // = b*4096 + n0 + px
        *(uint4*)(xrb + row * 256 + q * 8) = raw;

        float mu = muS[px], rs = rsS[px];
        const float4 w0 = *(const float4*)(nw + q * 8);
        const float4 w1 = *(const float4*)(nw + q * 8 + 4);
        const float4 b0 = *(const float4*)(nb + q * 8);
        const float4 b1 = *(const float4*)(nb + q * 8 + 4);
        float e0 = (bf_lo(raw.x) - mu) * rs * w0.x + b0.x;
        float e1 = (bf_hi(raw.x) - mu) * rs * w0.y + b0.y;
        float e2 = (bf_lo(raw.y) - mu) * rs * w0.z + b0.z;
        float e3 = (bf_hi(raw.y) - mu) * rs * w0.w + b0.w;
        float e4 = (bf_lo(raw.z) - mu) * rs * w1.x + b1.x;
        float e5 = (bf_hi(raw.z) - mu) * rs * w1.y + b1.y;
        float e6 = (bf_lo(raw.w) - mu) * rs * w1.z + b1.z;
        float e7 = (bf_hi(raw.w) - mu) * rs * w1.w + b1.w;
        uint4 o;
        o.x = pack_bf(e0, e1); o.y = pack_bf(e2, e3);
        o.z = pack_bf(e4, e5); o.w = pack_bf(e6, e7);
        *(uint4*)(xnb + row * 256 + q * 8) = o;
    }
}

// ---------------------------------------------------------------------------
// qkvconv: single-wave blocks, job = blockIdx&3 (0=Q 1=K 2=V 3=conv), 32-px
// group = blockIdx>>2. No barriers; wave-private LDS transpose (stride 33).
// grid 1024 x 64.
// ---------------------------------------------------------------------------
__global__ __launch_bounds__(64) void qkvconv_kernel(
    const ushort* __restrict__ xnb, const ushort* __restrict__ xrb,
    const ushort* __restrict__ qkvw_b, const ushort* __restrict__ c1w_b,
    const float* __restrict__ c1b, const float* __restrict__ c2w,
    const float* __restrict__ c2b,
    ushort* __restrict__ Qb, ushort* __restrict__ Kb, ushort* __restrict__ Vsw,
    float* __restrict__ dynb)
{
    __shared__ float tr[32 * 33];
    const int t  = threadIdx.x;
    const int m  = t & 31;            // A-row / C-col index
    const int h  = t >> 5;            // k-slot half
    const int bi = blockIdx.x;
    const int j  = bi & 3;            // job
    const int pg = bi >> 2;           // 32-px group 0..255
    const int b  = pg >> 7;
    const int n0 = (pg & 127) * 32;

    if (j < 3) {
        const ushort* bp  = xnb + ((size_t)pg * 32 + m) * 256 + h * 8;
        const ushort* ap0 = qkvw_b + ((size_t)(j * 64 + m)) * 256 + h * 8;
        const ushort* ap1 = ap0 + 32 * 256;
        f32x16 acc0, acc1;
        #pragma unroll
        for (int i = 0; i < 16; ++i) { acc0[i] = 0.f; acc1[i] = 0.f; }
        #pragma unroll 4
        for (int ks = 0; ks < 16; ++ks) {
            bf16x8 bf = *(const bf16x8*)(bp  + ks * 16);
            bf16x8 a0 = *(const bf16x8*)(ap0 + ks * 16);
            bf16x8 a1 = *(const bf16x8*)(ap1 + ks * 16);
            acc0 = __builtin_amdgcn_mfma_f32_32x32x16_bf16(a0, bf, acc0, 0, 0, 0);
            acc1 = __builtin_amdgcn_mfma_f32_32x32x16_bf16(a1, bf, acc1, 0, 0, 0);
        }
        for (int ti = 0; ti < 2; ++ti) {
            const f32x16& A = ti ? acc1 : acc0;
            #pragma unroll
            for (int r = 0; r < 16; ++r)
                tr[((r & 3) + 8 * (r >> 2) + 4 * h) * 33 + m] = A[r];
            if (j < 2) {
                ushort* dst = (j == 0) ? Qb : Kb;
                #pragma unroll
                for (int it = 0; it < 2; ++it) {
                    int unit = it * 2 + h;            // 0..3
                    int hl = unit >> 1, half = unit & 1;
                    float v0 = tr[(hl * 16 + half * 8 + 0) * 33 + m];
                    float v1 = tr[(hl * 16 + half * 8 + 1) * 33 + m];
                    float v2 = tr[(hl * 16 + half * 8 + 2) * 33 + m];
                    float v3 = tr[(hl * 16 + half * 8 + 3) * 33 + m];
                    float v4 = tr[(hl * 16 + half * 8 + 4) * 33 + m];
                    float v5 = tr[(hl * 16 + half * 8 + 5) * 33 + m];
                    float v6 = tr[(hl * 16 + half * 8 + 6) * 33 + m];
                    float v7 = tr[(hl * 16 + half * 8 + 7) * 33 + m];
                    uint4 pk;
                    pk.x = pack_bf(v0, v1); pk.y = pack_bf(v2, v3);
                    pk.z = pack_bf(v4, v5); pk.w = pack_bf(v6, v7);
                    int head = ti * 2 + hl;
                    *(uint4*)(dst + ((size_t)(b * 4 + head) * 4096 + n0 + m) * 16 + half * 8) = pk;
                }
            } else {
                int d = t & 15, u = t >> 4;
                #pragma unroll
                for (int it = 0; it < 4; ++it) {
                    int unit = it * 4 + u;            // 0..15
                    int hl = unit >> 3, sg = unit & 7;
                    float v0 = tr[(hl * 16 + d) * 33 + sg * 4 + 0];
                    float v1 = tr[(hl * 16 + d) * 33 + sg * 4 + 1];
                    float v2 = tr[(hl * 16 + d) * 33 + sg * 4 + 2];
                    float v3 = tr[(hl * 16 + d) * 33 + sg * 4 + 3];
                    uint2 pk; pk.x = pack_bf(v0, v1); pk.y = pack_bf(v2, v3);
                    int head = ti * 2 + hl;
                    *(uint2*)(Vsw + (((size_t)(b * 4 + head) * 1024 + (pg & 127) * 8 + sg) * 16 + d) * 4) = pk;
                }
            }
        }
    } else {
        // conv branch: 4 tiles x 16 ksteps on raw x
        const ushort* bp = xrb + ((size_t)pg * 32 + m) * 256 + h * 8;
        f32x16 acc[4];
        #pragma unroll
        for (int ti = 0; ti < 4; ++ti)
            #pragma unroll
            for (int i = 0; i < 16; ++i) acc[ti][i] = 0.f;
        #pragma unroll 2
        for (int ks = 0; ks < 16; ++ks) {
            bf16x8 bf = *(const bf16x8*)(bp + ks * 16);
            #pragma unroll
            for (int ti = 0; ti < 4; ++ti) {
                bf16x8 a = *(const bf16x8*)(c1w_b + ((size_t)(ti * 32 + m)) * 256 + ks * 16 + h * 8);
                acc[ti] = __builtin_amdgcn_mfma_f32_32x32x16_bf16(a, bf, acc[ti], 0, 0, 0);
            }
        }
        float partial = 0.f;
        for (int ti = 0; ti < 4; ++ti) {
            #pragma unroll
            for (int r = 0; r < 16; ++r)
                tr[((r & 3) + 8 * (r >> 2) + 4 * h) * 33 + m] = acc[ti][r];
            #pragma unroll
            for (int i = 0; i < 16; ++i) {
                int og = ti * 32 + h * 16 + i;
                partial += fmaxf(tr[(h * 16 + i) * 33 + m] + c1b[og], 0.f) * c2w[og];
            }
        }
        float tot = partial + __shfl_xor(partial, 32);
        if (t < 32) dynb[(size_t)b * 4096 + n0 + m] = c2b[0] + tot;
    }
}

// ---------------------------------------------------------------------------
// attn: MFMA flash attention, no LDS, no barriers, no online max.
// P packed with truncation (self-consistent with l ones-row).
// grid 512 x 256.
// ---------------------------------------------------------------------------
__global__ __launch_bounds__(256) void attn_kernel(
    const ushort* __restrict__ Qb, const ushort* __restrict__ Kb,
    const ushort* __restrict__ Vsw, float* __restrict__ AO2)
{
    const int t   = threadIdx.x;
    const int lid = t & 63;
    const int w   = t >> 6;
    const int c   = lid & 31;
    const int h   = lid >> 5;

    const int bi = blockIdx.x;
    const int kb = bi & 1;
    const int qb = (bi >> 1) & 31;
    const int bh = bi >> 6;
    const int nq = qb * 128 + w * 32;

    const bf16x8 qf = *(const bf16x8*)(Qb + ((size_t)bh * 4096 + nq + c) * 16 + h * 8);

    f32x16 oacc, zf;
    #pragma unroll
    for (int i = 0; i < 16; ++i) { oacc[i] = 0.f; zf[i] = 0.f; }

    const ushort* kp = Kb + ((size_t)bh * 4096 + kb * 2048 + c) * 16 + h * 8;
    const ushort* vb = Vsw + (size_t)bh * 65536 + ((size_t)kb * 512 + h) * 64 + c * 4;

    #pragma unroll 2
    for (int ch = 0; ch < 64; ++ch) {
        const bf16x8 kf = *(const bf16x8*)kp;
        f32x16 s = __builtin_amdgcn_mfma_f32_32x32x16_bf16(kf, qf, zf, 0, 0, 0);

        BF8 p1, p2;
        #pragma unroll
        for (int jj = 0; jj < 4; ++jj) {
            p1.u[jj] = pack_bf_trunc(__builtin_amdgcn_exp2f(s[2*jj]),   __builtin_amdgcn_exp2f(s[2*jj+1]));
            p2.u[jj] = pack_bf_trunc(__builtin_amdgcn_exp2f(s[8+2*jj]), __builtin_amdgcn_exp2f(s[8+2*jj+1]));
        }

        BF8 a1, a2;
        if (c < 16) {
            const uint2 g1 = *(const uint2*)(vb);
            const uint2 g2 = *(const uint2*)(vb + 128);
            const uint2 g3 = *(const uint2*)(vb + 256);
            const uint2 g4 = *(const uint2*)(vb + 384);
            a1.u[0] = g1.x; a1.u[1] = g1.y; a1.u[2] = g2.x; a1.u[3] = g2.y;
            a2.u[0] = g3.x; a2.u[1] = g3.y; a2.u[2] = g4.x; a2.u[3] = g4.y;
        } else {
            const uint f = (c == 16) ? 0x3F803F80u : 0u;   // ones row -> l
            a1.u[0] = a1.u[1] = a1.u[2] = a1.u[3] = f;
            a2.u[0] = a2.u[1] = a2.u[2] = a2.u[3] = f;
        }

        oacc = __builtin_amdgcn_mfma_f32_32x32x16_bf16(a1.v, p1.v, oacc, 0, 0, 0);
        oacc = __builtin_amdgcn_mfma_f32_32x32x16_bf16(a2.v, p2.v, oacc, 0, 0, 0);

        kp += 512; vb += 512;
    }

    float* ao = AO2 + ((size_t)(kb * 8 + bh) * 4096 + nq + c) * 20;
    float4 s0; s0.x = oacc[0]; s0.y = oacc[1]; s0.z = oacc[2]; s0.w = oacc[3];
    float4 s1; s1.x = oacc[4]; s1.y = oacc[5]; s1.z = oacc[6]; s1.w = oacc[7];
    *(float4*)(ao + 4 * h)     = s0;     // d {0..3}+4h
    *(float4*)(ao + 8 + 4 * h) = s1;     // d {8..11}+4h
    if (h == 0) ao[16] = oacc[8];        // l
}

// ---------------------------------------------------------------------------
// final: MFMA out-proj. Per kstep ks (=head), lanes build B-frag from AO2
// (merge kb splits, /l, *dyn). A = out_w bf16. Epilogue via LDS transpose ->
// coalesced sigmoid(g*y + x) writes. grid 256 x 256.
// ---------------------------------------------------------------------------
__global__ __launch_bounds__(256) void final_kernel(
    const float* __restrict__ AO2, const float* __restrict__ dynb,
    const ushort* __restrict__ ow_b, const float* __restrict__ x,
    const float* __restrict__ gamma, float* __restrict__ out)
{
    __shared__ float trans[4][32 * 33];
    const int t    = threadIdx.x;
    const int w    = t >> 6;
    const int lane = t & 63;
    const int m    = lane & 31;      // px / A-row
    const int h    = lane >> 5;
    const int pg   = blockIdx.x;
    const int b    = pg >> 7;
    const int n0   = (pg & 127) * 32;
    float* tr = trans[w];

    const float dyn_px = dynb[(size_t)b * 4096 + n0 + m];
    const ushort* a0p = ow_b + ((size_t)(w * 64 + m)) * 64 + h * 8;
    const ushort* a1p = a0p + 32 * 64;

    f32x16 acc0, acc1;
    #pragma unroll
    for (int i = 0; i < 16; ++i) { acc0[i] = 0.f; acc1[i] = 0.f; }

    #pragma unroll
    for (int ks = 0; ks < 4; ++ks) {
        const float* r0 = AO2 + ((size_t)(b * 4 + ks) * 4096 + n0 + m) * 20;
        const float* r1 = r0 + (size_t)8 * 4096 * 20;
        float l   = r0[16] + r1[16];
        float fac = dyn_px / l;
        float4 u0 = *(const float4*)(r0 + h * 8);
        float4 u1 = *(const float4*)(r0 + h * 8 + 4);
        float4 t0 = *(const float4*)(r1 + h * 8);
        float4 t1 = *(const float4*)(r1 + h * 8 + 4);
        float e0 = (u0.x + t0.x) * fac, e1 = (u0.y + t0.y) * fac;
        float e2 = (u0.z + t0.z) * fac, e3 = (u0.w + t0.w) * fac;
        float e4 = (u1.x + t1.x) * fac, e5 = (u1.y + t1.y) * fac;
        float e6 = (u1.z + t1.z) * fac, e7 = (u1.w + t1.w) * fac;
        BF8 bfr;
        bfr.u[0] = pack_bf(e0, e1); bfr.u[1] = pack_bf(e2, e3);
        bfr.u[2] = pack_bf(e4, e5); bfr.u[3] = pack_bf(e6, e7);
        bf16x8 af0 = *(const bf16x8*)(a0p + ks * 16);
        bf16x8 af1 = *(const bf16x8*)(a1p + ks * 16);
        acc0 = __builtin_amdgcn_mfma_f32_32x32x16_bf16(af0, bfr.v, acc0, 0, 0, 0);
        acc1 = __builtin_amdgcn_mfma_f32_32x32x16_bf16(af1, bfr.v, acc1, 0, 0, 0);
    }

    const float g = gamma[0];
    for (int ti = 0; ti < 2; ++ti) {
        const f32x16& A = ti ? acc1 : acc0;
        #pragma unroll
        for (int r = 0; r < 16; ++r)
            tr[((r & 3) + 8 * (r >> 2) + 4 * h) * 33 + m] = A[r];
        int ob = w * 64 + ti * 32;
        #pragma unroll 4
        for (int it = 0; it < 16; ++it) {
            int o = it * 2 + h;
            float vv = tr[o * 33 + m];
            size_t idx = ((size_t)b * 256 + ob + o) * 4096 + n0 + m;
            float z = g * vv + x[idx];
            out[idx] = 1.f / (1.f + __builtin_amdgcn_exp2f(-z * LOG2E));
        }
    }
}

// ---------------------------------------------------------------------------
extern "C" void kernel_launch(void* const* d_in, const int* in_sizes, int n_in,
                              void* d_out, int out_size, void* d_ws, size_t ws_size,
                              hipStream_t stream)
{
    const float* x      = (const float*)d_in[0];
    const float* norm_w = (const float*)d_in[1];
    const float* norm_b = (const float*)d_in[2];
    const float* qkv_w  = (const float*)d_in[3];
    const float* out_w  = (const float*)d_in[4];
    const float* c1w    = (const float*)d_in[5];
    const float* c1b    = (const float*)d_in[6];
    const float* c2w    = (const float*)d_in[7];
    const float* c2b    = (const float*)d_in[8];
    const float* gamma  = (const float*)d_in[9];

    char* ws = (char*)d_ws;
    ushort* Qb     = (ushort*)ws;                       // 524288 ush (1 MB)
    ushort* Kb     = Qb + 524288;
    ushort* Vsw    = Kb + 524288;                       // 524288 ush
    ushort* qkvw_b = Vsw + 524288;                      // 49152
    ushort* c1w_b  = qkvw_b + 49152;                    // 32768
    ushort* ow_b   = c1w_b + 32768;                     // 16384
    float*  dynb   = (float*)(ws + 3342336);            // 8192 floats
    // region X (byte 3375104): xn/xr live ln->qkvconv; AO2 aliases xn after
    ushort* xnb    = (ushort*)(ws + 3375104);           // 2097152 ush (4 MB)
    ushort* xrb    = xnb + 2097152;                     // 4 MB
    float*  AO2    = (float*)(ws + 3375104);            // 2*8*4096*20 fp32 (5.24 MB)

    hipLaunchKernelGGL(ln_cast_kernel, dim3(352), dim3(256), 0, stream,
                       x, norm_w, norm_b, qkv_w, c1w, out_w, xnb, xrb, qkvw_b, c1w_b, ow_b);
    hipLaunchKernelGGL(qkvconv_kernel, dim3(1024), dim3(64), 0, stream,
                       xnb, xrb, qkvw_b, c1w_b, c1b, c2w, c2b, Qb, Kb, Vsw, dynb);
    hipLaunchKernelGGL(attn_kernel, dim3(512), dim3(256), 0, stream,
                       Qb, Kb, Vsw, AO2);
    hipLaunchKernelGGL(final_kernel, dim3(256), dim3(256), 0, stream,
                       AO2, dynb, ow_b, x, gamma, (float*)d_out);
}

// Round 5
// 140.366 us; speedup vs baseline: 1.0086x; 1.0086x over previous
//
#include <hip/hip_runtime.h>
#include <cstdint>
#include <cstddef>

#define LOG2E 1.44269504088896340736f

typedef float  f32x16 __attribute__((ext_vector_type(16)));
typedef __bf16 bf16x8 __attribute__((ext_vector_type(8)));

union BF8 { bf16x8 v; uint u[4]; ushort us[8]; };

// pack two floats to bf16 pair (round-half-up), a -> lo16, b -> hi16
__device__ __forceinline__ uint pack_bf(float a, float b) {
    uint ua = __float_as_uint(a) + 0x8000u;
    uint ub = __float_as_uint(b) + 0x8000u;
    return __builtin_amdgcn_perm(ub, ua, 0x07060302u);
}
// truncating pack (1 op). Used for P only: l sums the same truncated P via the
// ones-row, so the /l normalization cancels the truncation bias to first order.
__device__ __forceinline__ uint pack_bf_trunc(float a, float b) {
    return __builtin_amdgcn_perm(__float_as_uint(b), __float_as_uint(a), 0x07060302u);
}

// ---------------------------------------------------------------------------
// fused_pre: per 32-px tile — LayerNorm (fp32) -> bf16 xn/xr tiles in LDS ->
// 4 waves run MFMA jobs (0=Q 1=K 2=V 3=conv) with A-frags packed on the fly
// from fp32 weights. Outputs Qb/Kb [bh][n][16], Vsw swizzled, dynb.
// grid 256 x 256.
// ---------------------------------------------------------------------------
__global__ __launch_bounds__(256) void fused_pre_kernel(
    const float* __restrict__ x, const float* __restrict__ nw, const float* __restrict__ nb,
    const float* __restrict__ qkv_w, const float* __restrict__ c1w,
    const float* __restrict__ c1b, const float* __restrict__ c2w, const float* __restrict__ c2b,
    ushort* __restrict__ Qb, ushort* __restrict__ Kb, ushort* __restrict__ Vsw,
    float* __restrict__ dynb)
{
    __shared__ uint  xpn[32 * 144];   // normalized bf16 pairs [px][c/2], stride 144
    __shared__ uint  xpr[32 * 144];   // raw bf16 pairs
    __shared__ float trans[4][32 * 33];
    __shared__ float red1[256], red2[256];
    __shared__ float muS[32], rsS[32];
    __shared__ float nwS[256], nbS[256];

    const int t  = threadIdx.x;
    const int pg = blockIdx.x;
    const int b  = pg >> 7;
    const int n0 = (pg & 127) * 32;

    // ---- phase 1: LayerNorm + bf16 pack into LDS ----
    {
        const int j  = t & 31;          // px
        const int cg = t >> 5;          // channel group (32 c)
        const size_t xb = (size_t)b * 256 * 4096 + n0 + j;
        nwS[t] = nw[t]; nbS[t] = nb[t];

        float v[32];
        #pragma unroll
        for (int i = 0; i < 32; ++i) v[i] = x[xb + (size_t)(cg * 32 + i) * 4096];
        float s1 = 0.f, s2 = 0.f;
        #pragma unroll
        for (int i = 0; i < 32; ++i) { s1 += v[i]; s2 += v[i] * v[i]; }
        #pragma unroll
        for (int i = 0; i < 16; ++i)
            xpr[j * 144 + cg * 16 + i] = pack_bf(v[2 * i], v[2 * i + 1]);
        red1[t] = s1; red2[t] = s2;
        __syncthreads();
        if (t < 32) {
            float a = 0.f, q = 0.f;
            #pragma unroll
            for (int g2 = 0; g2 < 8; ++g2) { a += red1[g2 * 32 + t]; q += red2[g2 * 32 + t]; }
            float mu  = a * (1.f / 256.f);
            float var = q * (1.f / 256.f) - mu * mu;
            muS[t] = mu; rsS[t] = rsqrtf(fmaxf(var, 0.f) + 1e-5f);
        }
        __syncthreads();
        float mu = muS[j], rs = rsS[j];
        #pragma unroll
        for (int i = 0; i < 16; ++i) {
            int c0 = cg * 32 + 2 * i;
            float e0 = (v[2 * i]     - mu) * rs * nwS[c0]     + nbS[c0];
            float e1 = (v[2 * i + 1] - mu) * rs * nwS[c0 + 1] + nbS[c0 + 1];
            xpn[j * 144 + cg * 16 + i] = pack_bf(e0, e1);
        }
        __syncthreads();
    }

    // ---- phase 2: per-wave MFMA jobs ----
    const int w    = t >> 6;
    const int lane = t & 63;
    const int m    = lane & 31;       // A-row / C-col
    const int h    = lane >> 5;       // k-slot half
    float* tr = trans[w];

    if (w < 3) {
        const uint*  bp  = xpn + m * 144 + h * 4;
        const float* w0p = qkv_w + (size_t)(w * 64 + m) * 256 + h * 8;
        const float* w1p = w0p + 32 * 256;
        const float sc = (w == 0) ? (0.25f * LOG2E) : 1.f;

        f32x16 acc0, acc1;
        #pragma unroll
        for (int i = 0; i < 16; ++i) { acc0[i] = 0.f; acc1[i] = 0.f; }

        #pragma unroll 4
        for (int ks = 0; ks < 16; ++ks) {
            uint4 bu = *(const uint4*)(bp + ks * 8);
            BF8 bfr; bfr.u[0] = bu.x; bfr.u[1] = bu.y; bfr.u[2] = bu.z; bfr.u[3] = bu.w;
            float4 a00 = *(const float4*)(w0p + ks * 16);
            float4 a01 = *(const float4*)(w0p + ks * 16 + 4);
            float4 a10 = *(const float4*)(w1p + ks * 16);
            float4 a11 = *(const float4*)(w1p + ks * 16 + 4);
            BF8 af0, af1;
            af0.u[0] = pack_bf(a00.x * sc, a00.y * sc);
            af0.u[1] = pack_bf(a00.z * sc, a00.w * sc);
            af0.u[2] = pack_bf(a01.x * sc, a01.y * sc);
            af0.u[3] = pack_bf(a01.z * sc, a01.w * sc);
            af1.u[0] = pack_bf(a10.x * sc, a10.y * sc);
            af1.u[1] = pack_bf(a10.z * sc, a10.w * sc);
            af1.u[2] = pack_bf(a11.x * sc, a11.y * sc);
            af1.u[3] = pack_bf(a11.z * sc, a11.w * sc);
            acc0 = __builtin_amdgcn_mfma_f32_32x32x16_bf16(af0.v, bfr.v, acc0, 0, 0, 0);
            acc1 = __builtin_amdgcn_mfma_f32_32x32x16_bf16(af1.v, bfr.v, acc1, 0, 0, 0);
        }

        for (int ti = 0; ti < 2; ++ti) {
            const f32x16& A = ti ? acc1 : acc0;
            #pragma unroll
            for (int r = 0; r < 16; ++r)
                tr[((r & 3) + 8 * (r >> 2) + 4 * h) * 33 + m] = A[r];
            if (w < 2) {
                ushort* dst = (w == 0) ? Qb : Kb;
                #pragma unroll
                for (int it = 0; it < 2; ++it) {
                    int unit = it * 2 + h;            // 0..3
                    int hl = unit >> 1, half = unit & 1;
                    float v0 = tr[(hl * 16 + half * 8 + 0) * 33 + m];
                    float v1 = tr[(hl * 16 + half * 8 + 1) * 33 + m];
                    float v2 = tr[(hl * 16 + half * 8 + 2) * 33 + m];
                    float v3 = tr[(hl * 16 + half * 8 + 3) * 33 + m];
                    float v4 = tr[(hl * 16 + half * 8 + 4) * 33 + m];
                    float v5 = tr[(hl * 16 + half * 8 + 5) * 33 + m];
                    float v6 = tr[(hl * 16 + half * 8 + 6) * 33 + m];
                    float v7 = tr[(hl * 16 + half * 8 + 7) * 33 + m];
                    uint4 pk;
                    pk.x = pack_bf(v0, v1); pk.y = pack_bf(v2, v3);
                    pk.z = pack_bf(v4, v5); pk.w = pack_bf(v6, v7);
                    int head = ti * 2 + hl;
                    *(uint4*)(dst + ((size_t)(b * 4 + head) * 4096 + n0 + m) * 16 + half * 8) = pk;
                }
            } else {
                int d = lane & 15, u = lane >> 4;
                #pragma unroll
                for (int it = 0; it < 4; ++it) {
                    int unit = it * 4 + u;            // 0..15
                    int hl = unit >> 3, sg = unit & 7;
                    float v0 = tr[(hl * 16 + d) * 33 + sg * 4 + 0];
                    float v1 = tr[(hl * 16 + d) * 33 + sg * 4 + 1];
                    float v2 = tr[(hl * 16 + d) * 33 + sg * 4 + 2];
                    float v3 = tr[(hl * 16 + d) * 33 + sg * 4 + 3];
                    uint2 pk; pk.x = pack_bf(v0, v1); pk.y = pack_bf(v2, v3);
                    int head = ti * 2 + hl;
                    *(uint2*)(Vsw + (((size_t)(b * 4 + head) * 1024 + (pg & 127) * 8 + sg) * 16 + d) * 4) = pk;
                }
            }
        }
    } else {
        // conv branch: 4 tiles x 16 ksteps on raw x (B from xpr)
        const uint* bp = xpr + m * 144 + h * 4;
        f32x16 acc[4];
        #pragma unroll
        for (int ti = 0; ti < 4; ++ti)
            #pragma unroll
            for (int i = 0; i < 16; ++i) acc[ti][i] = 0.f;
        #pragma unroll 2
        for (int ks = 0; ks < 16; ++ks) {
            uint4 bu = *(const uint4*)(bp + ks * 8);
            BF8 bfr; bfr.u[0] = bu.x; bfr.u[1] = bu.y; bfr.u[2] = bu.z; bfr.u[3] = bu.w;
            #pragma unroll
            for (int ti = 0; ti < 4; ++ti) {
                const float* wp = c1w + (size_t)(ti * 32 + m) * 256 + ks * 16 + h * 8;
                float4 a0 = *(const float4*)(wp);
                float4 a1 = *(const float4*)(wp + 4);
                BF8 af;
                af.u[0] = pack_bf(a0.x, a0.y); af.u[1] = pack_bf(a0.z, a0.w);
                af.u[2] = pack_bf(a1.x, a1.y); af.u[3] = pack_bf(a1.z, a1.w);
                acc[ti] = __builtin_amdgcn_mfma_f32_32x32x16_bf16(af.v, bfr.v, acc[ti], 0, 0, 0);
            }
        }
        float partial = 0.f;
        for (int ti = 0; ti < 4; ++ti) {
            #pragma unroll
            for (int r = 0; r < 16; ++r)
                tr[((r & 3) + 8 * (r >> 2) + 4 * h) * 33 + m] = acc[ti][r];
            #pragma unroll
            for (int i = 0; i < 16; ++i) {
                int og = ti * 32 + h * 16 + i;
                partial += fmaxf(tr[(h * 16 + i) * 33 + m] + c1b[og], 0.f) * c2w[og];
            }
        }
        float tot = partial + __shfl_xor(partial, 32);
        if (lane < 32) dynb[(size_t)b * 4096 + n0 + m] = c2b[0] + tot;
    }
}

// ---------------------------------------------------------------------------
// attn: MFMA flash attention, no LDS, no barriers, no online max.
// P packed with truncation (self-consistent with l ones-row).
// grid 512 x 256.
// ---------------------------------------------------------------------------
__global__ __launch_bounds__(256) void attn_kernel(
    const ushort* __restrict__ Qb, const ushort* __restrict__ Kb,
    const ushort* __restrict__ Vsw, float* __restrict__ AO2)
{
    const int t   = threadIdx.x;
    const int lid = t & 63;
    const int w   = t >> 6;
    const int c   = lid & 31;
    const int h   = lid >> 5;

    const int bi = blockIdx.x;
    const int kb = bi & 1;
    const int qb = (bi >> 1) & 31;
    const int bh = bi >> 6;
    const int nq = qb * 128 + w * 32;

    const bf16x8 qf = *(const bf16x8*)(Qb + ((size_t)bh * 4096 + nq + c) * 16 + h * 8);

    f32x16 oacc, zf;
    #pragma unroll
    for (int i = 0; i < 16; ++i) { oacc[i] = 0.f; zf[i] = 0.f; }

    const ushort* kp = Kb + ((size_t)bh * 4096 + kb * 2048 + c) * 16 + h * 8;
    const ushort* vb = Vsw + (size_t)bh * 65536 + ((size_t)kb * 512 + h) * 64 + c * 4;

    #pragma unroll 2
    for (int ch = 0; ch < 64; ++ch) {
        const bf16x8 kf = *(const bf16x8*)kp;
        f32x16 s = __builtin_amdgcn_mfma_f32_32x32x16_bf16(kf, qf, zf, 0, 0, 0);

        BF8 p1, p2;
        #pragma unroll
        for (int jj = 0; jj < 4; ++jj) {
            p1.u[jj] = pack_bf_trunc(__builtin_amdgcn_exp2f(s[2*jj]),   __builtin_amdgcn_exp2f(s[2*jj+1]));
            p2.u[jj] = pack_bf_trunc(__builtin_amdgcn_exp2f(s[8+2*jj]), __builtin_amdgcn_exp2f(s[8+2*jj+1]));
        }

        BF8 a1, a2;
        if (c < 16) {
            const uint2 g1 = *(const uint2*)(vb);
            const uint2 g2 = *(const uint2*)(vb + 128);
            const uint2 g3 = *(const uint2*)(vb + 256);
            const uint2 g4 = *(const uint2*)(vb + 384);
            a1.u[0] = g1.x; a1.u[1] = g1.y; a1.u[2] = g2.x; a1.u[3] = g2.y;
            a2.u[0] = g3.x; a2.u[1] = g3.y; a2.u[2] = g4.x; a2.u[3] = g4.y;
        } else {
            const uint f = (c == 16) ? 0x3F803F80u : 0u;   // ones row -> l
            a1.u[0] = a1.u[1] = a1.u[2] = a1.u[3] = f;
            a2.u[0] = a2.u[1] = a2.u[2] = a2.u[3] = f;
        }

        oacc = __builtin_amdgcn_mfma_f32_32x32x16_bf16(a1.v, p1.v, oacc, 0, 0, 0);
        oacc = __builtin_amdgcn_mfma_f32_32x32x16_bf16(a2.v, p2.v, oacc, 0, 0, 0);

        kp += 512; vb += 512;
    }

    float* ao = AO2 + ((size_t)(kb * 8 + bh) * 4096 + nq + c) * 20;
    float4 s0; s0.x = oacc[0]; s0.y = oacc[1]; s0.z = oacc[2]; s0.w = oacc[3];
    float4 s1; s1.x = oacc[4]; s1.y = oacc[5]; s1.z = oacc[6]; s1.w = oacc[7];
    *(float4*)(ao + 4 * h)     = s0;     // d {0..3}+4h
    *(float4*)(ao + 8 + 4 * h) = s1;     // d {8..11}+4h
    if (h == 0) ao[16] = oacc[8];        // l
}

// ---------------------------------------------------------------------------
// final: MFMA out-proj. Per kstep ks (=head), lanes build B-frag from AO2
// (merge kb splits, /l, *dyn). A = out_w fp32 packed on the fly. Epilogue via
// LDS transpose -> coalesced sigmoid(g*y + x) writes. grid 256 x 256.
// ---------------------------------------------------------------------------
__global__ __launch_bounds__(256) void final_kernel(
    const float* __restrict__ AO2, const float* __restrict__ dynb,
    const float* __restrict__ out_w, const float* __restrict__ x,
    const float* __restrict__ gamma, float* __restrict__ out)
{
    __shared__ float trans[4][32 * 33];
    const int t    = threadIdx.x;
    const int w    = t >> 6;
    const int lane = t & 63;
    const int m    = lane & 31;      // px / A-row
    const int h    = lane >> 5;
    const int pg   = blockIdx.x;
    const int b    = pg >> 7;
    const int n0   = (pg & 127) * 32;
    float* tr = trans[w];

    const float dyn_px = dynb[(size_t)b * 4096 + n0 + m];
    const float* a0p = out_w + (size_t)(w * 64 + m) * 64 + h * 8;
    const float* a1p = a0p + 32 * 64;

    f32x16 acc0, acc1;
    #pragma unroll
    for (int i = 0; i < 16; ++i) { acc0[i] = 0.f; acc1[i] = 0.f; }

    #pragma unroll
    for (int ks = 0; ks < 4; ++ks) {
        const float* r0 = AO2 + ((size_t)(b * 4 + ks) * 4096 + n0 + m) * 20;
        const float* r1 = r0 + (size_t)8 * 4096 * 20;
        float l   = r0[16] + r1[16];
        float fac = dyn_px / l;
        float4 u0 = *(const float4*)(r0 + h * 8);
        float4 u1 = *(const float4*)(r0 + h * 8 + 4);
        float4 t0 = *(const float4*)(r1 + h * 8);
        float4 t1 = *(const float4*)(r1 + h * 8 + 4);
        float e0 = (u0.x + t0.x) * fac, e1 = (u0.y + t0.y) * fac;
        float e2 = (u0.z + t0.z) * fac, e3 = (u0.w + t0.w) * fac;
        float e4 = (u1.x + t1.x) * fac, e5 = (u1.y + t1.y) * fac;
        float e6 = (u1.z + t1.z) * fac, e7 = (u1.w + t1.w) * fac;
        BF8 bfr;
        bfr.u[0] = pack_bf(e0, e1); bfr.u[1] = pack_bf(e2, e3);
        bfr.u[2] = pack_bf(e4, e5); bfr.u[3] = pack_bf(e6, e7);

        float4 f00 = *(const float4*)(a0p + ks * 16);
        float4 f01 = *(const float4*)(a0p + ks * 16 + 4);
        float4 f10 = *(const float4*)(a1p + ks * 16);
        float4 f11 = *(const float4*)(a1p + ks * 16 + 4);
        BF8 af0, af1;
        af0.u[0] = pack_bf(f00.x, f00.y); af0.u[1] = pack_bf(f00.z, f00.w);
        af0.u[2] = pack_bf(f01.x, f01.y); af0.u[3] = pack_bf(f01.z, f01.w);
        af1.u[0] = pack_bf(f10.x, f10.y); af1.u[1] = pack_bf(f10.z, f10.w);
        af1.u[2] = pack_bf(f11.x, f11.y); af1.u[3] = pack_bf(f11.z, f11.w);

        acc0 = __builtin_amdgcn_mfma_f32_32x32x16_bf16(af0.v, bfr.v, acc0, 0, 0, 0);
        acc1 = __builtin_amdgcn_mfma_f32_32x32x16_bf16(af1.v, bfr.v, acc1, 0, 0, 0);
    }

    const float g = gamma[0];
    for (int ti = 0; ti < 2; ++ti) {
        const f32x16& A = ti ? acc1 : acc0;
        #pragma unroll
        for (int r = 0; r < 16; ++r)
            tr[((r & 3) + 8 * (r >> 2) + 4 * h) * 33 + m] = A[r];
        int ob = w * 64 + ti * 32;
        #pragma unroll 4
        for (int it = 0; it < 16; ++it) {
            int o = it * 2 + h;
            float vv = tr[o * 33 + m];
            size_t idx = ((size_t)b * 256 + ob + o) * 4096 + n0 + m;
            float z = g * vv + x[idx];
            out[idx] = 1.f / (1.f + __builtin_amdgcn_exp2f(-z * LOG2E));
        }
    }
}

// ---------------------------------------------------------------------------
extern "C" void kernel_launch(void* const* d_in, const int* in_sizes, int n_in,
                              void* d_out, int out_size, void* d_ws, size_t ws_size,
                              hipStream_t stream)
{
    const float* x      = (const float*)d_in[0];
    const float* norm_w = (const float*)d_in[1];
    const float* norm_b = (const float*)d_in[2];
    const float* qkv_w  = (const float*)d_in[3];
    const float* out_w  = (const float*)d_in[4];
    const float* c1w    = (const float*)d_in[5];
    const float* c1b    = (const float*)d_in[6];
    const float* c2w    = (const float*)d_in[7];
    const float* c2b    = (const float*)d_in[8];
    const float* gamma  = (const float*)d_in[9];

    char* ws = (char*)d_ws;
    ushort* Qb   = (ushort*)ws;                    // 524288 ush (1 MB)
    ushort* Kb   = Qb + 524288;                    // 1 MB
    ushort* Vsw  = Kb + 524288;                    // 1 MB
    float*  dynb = (float*)(ws + 3145728);         // 8192 fp32 (32 KB)
    float*  AO2  = (float*)(ws + 3178496);         // 2*8*4096*20 fp32 (5.24 MB)

    hipLaunchKernelGGL(fused_pre_kernel, dim3(256), dim3(256), 0, stream,
                       x, norm_w, norm_b, qkv_w, c1w, c1b, c2w, c2b, Qb, Kb, Vsw, dynb);
    hipLaunchKernelGGL(attn_kernel, dim3(512), dim3(256), 0, stream,
                       Qb, Kb, Vsw, AO2);
    hipLaunchKernelGGL(final_kernel, dim3(256), dim3(256), 0, stream,
                       AO2, dynb, out_w, x, gamma, (float*)d_out);
}